// Round 3
// baseline (936.268 us; speedup 1.0000x reference)
//
#include <hip/hip_runtime.h>
#include <stdint.h>

// CCLayer: ZPi (288 x 262144) f32, U (256 x 32) f32, alpha (32) f32.
// Z = ZPi[:256], Pi = ZPi[256:].
// out[:256] = Z * sum_pi + U @ ((alpha - U^T Z) * Pi);  out[256:] = Pi.
//
// v4: kill exposed HBM latency with explicit register double-buffering.
// v3 counters: traffic ideal (586 MB ~= 604 MB roofline) but dur 337 us vs
// 93 us BW floor; VALUBusy 17.6% x 337 us ~= pure-FMA cycle count => waves
// stall with ZERO bytes in flight during every 512-FMA block (unroll-8 loop
// does not pipeline across iterations). Fix: fully-unrolled chunk loop, two
// named 8xfloat2 buffers, chunk c+1 loads issued BEFORE chunk c FMAs (both
// passes). Chunk-0 loads hoisted above the Pi phase; pass-2 chunk 0
// prefetched under the w-phase barriers (L3 hits). pi[] moved to LDS to stay
// under the 128-VGPR / 4-wave-per-SIMD cliff.
//
// Mapping: block = 256 thr = 4 waves, tile = 128 cols; lane owns cols
// 2*lane, 2*lane+1; wave q owns d-rows q*64..q*64+63. Cross-wave utz
// reduction via ds_add_f32. LDS 34 KB -> 4 blocks/CU.

#define NCOLS 262144
#define DROWS 256
#define PROWS 32
#define TILE  128
#define NWAVE 4
#define RPW   64   // d-rows per wave
#define CHUNK 8
#define NCHUNK (RPW / CHUNK)

typedef float v2f __attribute__((ext_vector_type(2)));

__global__ __launch_bounds__(256, 4) void CCLayer_kernel(
    const float* __restrict__ ZPi,
    const float* __restrict__ U,
    const float* __restrict__ alpha,
    float* __restrict__ out)
{
    __shared__ float wbuf[PROWS][TILE];   // 16 KB: utz partial sums -> w
    __shared__ float pibuf[PROWS][TILE];  // 16 KB: pi values for finalize
    __shared__ float sp[NWAVE][TILE];     //  2 KB: per-wave pi column sums

    const int lane = threadIdx.x & 63;
    const int q    = __builtin_amdgcn_readfirstlane((int)(threadIdx.x >> 6));
    const int n0   = blockIdx.x * TILE;
    const int c0   = lane * 2;               // column pair within tile
    const size_t gc = (size_t)n0 + c0;       // global column

    const float* zbase = ZPi + (size_t)(q * RPW) * NCOLS + gc;
    const float* ubase = U + q * RPW * PROWS;

    // ---- issue pass-1 chunk-0 Z loads FIRST (latency hides under Pi phase) ----
    v2f zb0[CHUNK], zb1[CHUNK];
    #pragma unroll
    for (int i = 0; i < CHUNK; ++i)
        zb0[i] = *(const v2f*)(zbase + (size_t)i * NCOLS);

    // ---- Pi: wave q owns rows q*8..q*8+7; passthrough + column partial sum ----
    {
        v2f ps = {0.f, 0.f};
        #pragma unroll
        for (int j = 0; j < 8; ++j) {
            const int p = q * 8 + j;
            const size_t off = (size_t)(DROWS + p) * NCOLS + gc;
            const v2f v = __builtin_nontemporal_load((const v2f*)(ZPi + off));
            __builtin_nontemporal_store(v, (v2f*)(out + off));
            *(v2f*)&pibuf[p][c0] = v;
            ps += v;
        }
        sp[q][c0]     = ps.x;
        sp[q][c0 + 1] = ps.y;
    }

    // ---- zero wbuf (4096 floats, 256 threads x 4 float4) ----
    {
        float4* wb4 = (float4*)&wbuf[0][0];
        #pragma unroll
        for (int i = 0; i < 4; ++i)
            wb4[threadIdx.x + 256 * i] = make_float4(0.f, 0.f, 0.f, 0.f);
    }

    __syncthreads();   // wbuf zeroed + sp/pibuf visible

    // ---- pass 1: utz[p] partials, software-pipelined over 8 chunks ----
    v2f utz[PROWS];
    #pragma unroll
    for (int p = 0; p < PROWS; ++p) utz[p] = (v2f){0.f, 0.f};

    #pragma unroll
    for (int c = 0; c < NCHUNK; ++c) {
        v2f* cur = (c & 1) ? zb1 : zb0;    // folds: loop fully unrolled
        v2f* nxt = (c & 1) ? zb0 : zb1;
        if (c + 1 < NCHUNK) {              // prefetch next chunk BEFORE FMAs
            #pragma unroll
            for (int i = 0; i < CHUNK; ++i)
                nxt[i] = *(const v2f*)(zbase + (size_t)((c + 1) * CHUNK + i) * NCOLS);
        }
        #pragma unroll
        for (int i = 0; i < CHUNK; ++i) {
            const int d = c * CHUNK + i;
            const float* urow = ubase + d * PROWS;   // uniform -> s_load
            const v2f z2 = cur[i];
            #pragma unroll
            for (int p = 0; p < PROWS; ++p) {
                utz[p].x = __builtin_fmaf(urow[p], z2.x, utz[p].x);
                utz[p].y = __builtin_fmaf(urow[p], z2.y, utz[p].y);
            }
        }
    }
    #pragma unroll
    for (int p = 0; p < PROWS; ++p) {
        atomicAdd(&wbuf[p][c0],     utz[p].x);   // ds_add_f32
        atomicAdd(&wbuf[p][c0 + 1], utz[p].y);
    }

    // ---- prefetch pass-2 chunk 0 (L3 hits) under the w-phase barriers ----
    #pragma unroll
    for (int i = 0; i < CHUNK; ++i)
        zb0[i] = *(const v2f*)(zbase + (size_t)i * NCOLS);

    __syncthreads();

    // ---- finalize w rows q*8..q*8+7: w = (alpha - utz_total) * pi ----
    #pragma unroll
    for (int j = 0; j < 8; ++j) {
        const int p = q * 8 + j;
        const float a = alpha[p];                // uniform -> s_load
        wbuf[p][c0]     = (a - wbuf[p][c0])     * pibuf[p][c0];
        wbuf[p][c0 + 1] = (a - wbuf[p][c0 + 1]) * pibuf[p][c0 + 1];
    }

    __syncthreads();

    // ---- s (column pi-sum) and w into registers ----
    v2f s2 = {0.f, 0.f};
    #pragma unroll
    for (int qq = 0; qq < NWAVE; ++qq) {
        s2.x += sp[qq][c0];
        s2.y += sp[qq][c0 + 1];
    }
    v2f w[PROWS];
    #pragma unroll
    for (int p = 0; p < PROWS; ++p)
        w[p] = *(const v2f*)&wbuf[p][c0];

    // ---- pass 2: out[d] = s*z[d] + sum_p U[d][p]*w[p], pipelined, NT stores ----
    float* obase = out + (size_t)(q * RPW) * NCOLS + gc;
    #pragma unroll
    for (int c = 0; c < NCHUNK; ++c) {
        v2f* cur = (c & 1) ? zb1 : zb0;
        v2f* nxt = (c & 1) ? zb0 : zb1;
        if (c + 1 < NCHUNK) {              // prefetch next chunk BEFORE FMAs
            #pragma unroll
            for (int i = 0; i < CHUNK; ++i)
                nxt[i] = *(const v2f*)(zbase + (size_t)((c + 1) * CHUNK + i) * NCOLS);
        }
        #pragma unroll
        for (int i = 0; i < CHUNK; ++i) {
            const int d = c * CHUNK + i;
            const float* urow = ubase + d * PROWS;   // uniform -> s_load
            const v2f z2 = cur[i];
            v2f acc = {s2.x * z2.x, s2.y * z2.y};
            #pragma unroll
            for (int p = 0; p < PROWS; ++p) {
                acc.x = __builtin_fmaf(urow[p], w[p].x, acc.x);
                acc.y = __builtin_fmaf(urow[p], w[p].y, acc.y);
            }
            __builtin_nontemporal_store(acc, (v2f*)(obase + (size_t)d * NCOLS));
        }
    }
}

extern "C" void kernel_launch(void* const* d_in, const int* in_sizes, int n_in,
                              void* d_out, int out_size, void* d_ws, size_t ws_size,
                              hipStream_t stream) {
    const float* ZPi   = (const float*)d_in[0];
    const float* U     = (const float*)d_in[1];
    const float* alpha = (const float*)d_in[2];
    float* out = (float*)d_out;

    dim3 grid(NCOLS / TILE);   // 2048 blocks
    dim3 block(256);           // 4 waves
    CCLayer_kernel<<<grid, block, 0, stream>>>(ZPi, U, alpha, out);
}